// Round 4
// baseline (127.275 us; speedup 1.0000x reference)
//
#include <hip/hip_runtime.h>
#include <hip/hip_bf16.h>

// Shapes
#define BB 16
#define PP 64
#define NN 4096
#define DD 768

typedef __attribute__((ext_vector_type(4))) float f32x4;
typedef __attribute__((ext_vector_type(8))) __bf16 bf16x8;
typedef __attribute__((ext_vector_type(4))) __bf16 bf16x4;
typedef __attribute__((ext_vector_type(2))) __bf16 bf16x2;
typedef __attribute__((ext_vector_type(4))) _Float16 f16x4;

__device__ __forceinline__ f32x4 mfma16(bf16x8 a, bf16x8 b, f32x4 c) {
    return __builtin_amdgcn_mfma_f32_16x16x32_bf16(a, b, c, 0, 0, 0);
}

// XOR swizzle for phase-1 K/Q tiles (b128 frag reads 2-way free)
__device__ __forceinline__ int SW(int r) { return ((r >> 3) & 3) << 3; }

// P buffer row stride (elems). 520 B = 16*32+8: softmax scalar writes spread
// the 4 hi-windows by 32 B each (2-way); frag reads stride 2*prow banks (2-way).
#define LP_STRIDE 260

// LDS layout (bytes):
//   [0,      32768)  lk: phase1 K tile [256][64] swizzled / phase2 V^T [64][256] swizzled
//   [32768,  40960)  lq: Q tile [64][64] swizzled
//   [40960,  74240)  lp: P [64][LP_STRIDE] bf16
//   [74240,  76288)  wred [8][64] f32
//   [76288,  76544)  mfin [64] f32
#define SM_BYTES 76544

// ---------------------------------------------------------------------------
// Fused: per (b, 256-token chunk): QK^T -> local softmax (P in LDS) -> PV.
// Writes fp16 partial [64 p][768 d] and per-chunk stats (m, l).
// grid 256 = 16 b x 16 chunks; block 512 (8 waves).
// ---------------------------------------------------------------------------
__global__ __launch_bounds__(512) void k_fused(const float* __restrict__ x,
                                               const float* __restrict__ q,
                                               float* __restrict__ statm,
                                               float* __restrict__ statl,
                                               _Float16* __restrict__ part) {
    const int b  = blockIdx.x >> 4;
    const int sp = blockIdx.x & 15;
    const int n0 = sp * 256;

    __shared__ char smem[SM_BYTES];
    __bf16* lk   = (__bf16*)smem;
    __bf16* lq   = (__bf16*)(smem + 32768);
    __bf16* lp   = (__bf16*)(smem + 40960);
    float*  wred = (float*)(smem + 74240);
    float*  mfin = (float*)(smem + 76288);

    const int t = threadIdx.x;
    const int w = t >> 6, lane = t & 63;
    const int l15 = lane & 15, hi = lane >> 4;

    const int rK = t >> 1, hK = t & 1;      // K-tile row / 32-float half
    const int rQ = (t & 127) >> 1, hQ = t & 1;

    f32x4 acc[4][2] = {};

    const size_t xrow = ((size_t)b * NN + n0 + rK) * DD + hK * 32;
    const size_t qrow = ((size_t)b * PP + rQ) * DD + hQ * 32;

    // ============================ Phase 1: QK^T ============================
    for (int kd = 0; kd < DD; kd += 64) {
        float4 tk[8], tq[8];
        #pragma unroll
        for (int i = 0; i < 8; ++i) tk[i] = *(const float4*)&x[xrow + kd + 4 * i];
        if (t < 128) {
            #pragma unroll
            for (int i = 0; i < 8; ++i) tq[i] = *(const float4*)&q[qrow + kd + 4 * i];
        }
        __syncthreads();
        #pragma unroll
        for (int j = 0; j < 4; ++j) {
            const float4 a = tk[2 * j], c = tk[2 * j + 1];
            bf16x8 h = {(__bf16)a.x, (__bf16)a.y, (__bf16)a.z, (__bf16)a.w,
                        (__bf16)c.x, (__bf16)c.y, (__bf16)c.z, (__bf16)c.w};
            *(bf16x8*)&lk[rK * 64 + ((hK * 32 + 8 * j) ^ SW(rK))] = h;
        }
        if (t < 128) {
            #pragma unroll
            for (int j = 0; j < 4; ++j) {
                const float4 a = tq[2 * j], c = tq[2 * j + 1];
                bf16x8 h = {(__bf16)a.x, (__bf16)a.y, (__bf16)a.z, (__bf16)a.w,
                            (__bf16)c.x, (__bf16)c.y, (__bf16)c.z, (__bf16)c.w};
                *(bf16x8*)&lq[rQ * 64 + ((hQ * 32 + 8 * j) ^ SW(rQ))] = h;
            }
        }
        __syncthreads();
        #pragma unroll
        for (int ks = 0; ks < 2; ++ks) {
            bf16x8 af[4], bfr[2];
            #pragma unroll
            for (int am = 0; am < 4; ++am) {
                const int r = am * 16 + l15;
                af[am] = *(bf16x8*)&lq[r * 64 + ((ks * 32 + hi * 8) ^ SW(r))];
            }
            #pragma unroll
            for (int an = 0; an < 2; ++an) {
                const int r = w * 32 + an * 16 + l15;
                bfr[an] = *(bf16x8*)&lk[r * 64 + ((ks * 32 + hi * 8) ^ SW(r))];
            }
            #pragma unroll
            for (int am = 0; am < 4; ++am)
                #pragma unroll
                for (int an = 0; an < 2; ++an)
                    acc[am][an] = mfma16(af[am], bfr[an], acc[am][an]);
        }
    }

    // ==================== local softmax (P stays in LDS) ====================
    const float scale = 0.036084391824351615f;  // 768^-0.5
    float sv[4][2][4];
    #pragma unroll
    for (int am = 0; am < 4; ++am)
        #pragma unroll
        for (int an = 0; an < 2; ++an)
            #pragma unroll
            for (int j = 0; j < 4; ++j) sv[am][an][j] = acc[am][an][j] * scale;

    float pm[4][4];
    #pragma unroll
    for (int am = 0; am < 4; ++am)
        #pragma unroll
        for (int j = 0; j < 4; ++j) pm[am][j] = fmaxf(sv[am][0][j], sv[am][1][j]);
    #pragma unroll
    for (int off = 1; off < 16; off <<= 1)
        #pragma unroll
        for (int am = 0; am < 4; ++am)
            #pragma unroll
            for (int j = 0; j < 4; ++j) pm[am][j] = fmaxf(pm[am][j], __shfl_xor(pm[am][j], off));
    if (l15 == 0)
        #pragma unroll
        for (int am = 0; am < 4; ++am)
            #pragma unroll
            for (int j = 0; j < 4; ++j) wred[w * 64 + am * 16 + hi * 4 + j] = pm[am][j];
    __syncthreads();
    if (t < 64) {
        float m = wred[t];
        #pragma unroll
        for (int ww = 1; ww < 8; ++ww) m = fmaxf(m, wred[ww * 64 + t]);
        mfin[t] = m;
    }
    __syncthreads();

    float ls[4][4] = {};
    #pragma unroll
    for (int am = 0; am < 4; ++am)
        #pragma unroll
        for (int j = 0; j < 4; ++j) {
            const int p = am * 16 + hi * 4 + j;
            const float m = mfin[p];
            #pragma unroll
            for (int an = 0; an < 2; ++an) {
                const float e = __expf(sv[am][an][j] - m);
                ls[am][j] += e;
                lp[p * LP_STRIDE + w * 32 + an * 16 + l15] = (__bf16)e;
            }
        }
    #pragma unroll
    for (int off = 1; off < 16; off <<= 1)
        #pragma unroll
        for (int am = 0; am < 4; ++am)
            #pragma unroll
            for (int j = 0; j < 4; ++j) ls[am][j] += __shfl_xor(ls[am][j], off);
    if (l15 == 0)
        #pragma unroll
        for (int am = 0; am < 4; ++am)
            #pragma unroll
            for (int j = 0; j < 4; ++j) wred[w * 64 + am * 16 + hi * 4 + j] = ls[am][j];
    __syncthreads();
    if (t < 64) {
        float l = 0.f;
        #pragma unroll
        for (int ww = 0; ww < 8; ++ww) l += wred[ww * 64 + t];
        const size_t si = ((size_t)b * 16 + sp) * 64 + t;
        statm[si] = mfin[t];
        statl[si] = l;
    }
    // (next barrier below fences lp/stat writes before phase-2 reads)

    // ============================ Phase 2: PV ==============================
    // V^T staged into lk region: [64 d][256 n], col = n ^ ((d>>2 & 7)<<3).
    // wave w: ph = p-half, dq = 16-d column group. x re-read is L2/L3-hot.
    const int iiV = t & 15;      // d float4 col
    const int rrV = t >> 4;      // n-pair base
    const int ph = w >> 2, dq = w & 3;
    const int dRow = dq * 16 + l15;
    const int key = ((dRow >> 2) & 7) << 3;

    for (int d0 = 0; d0 < DD; d0 += 64) {
        float4 tv[8];
        #pragma unroll
        for (int pass = 0; pass < 4; ++pass) {
            const int n = pass * 64 + rrV * 2;
            tv[2 * pass]     = *(const float4*)&x[((size_t)b * NN + n0 + n) * DD + d0 + iiV * 4];
            tv[2 * pass + 1] = *(const float4*)&x[((size_t)b * NN + n0 + n + 1) * DD + d0 + iiV * 4];
        }
        __syncthreads();   // prev iter reads done; first iter: fences lp writes
        #pragma unroll
        for (int pass = 0; pass < 4; ++pass) {
            const int n = pass * 64 + rrV * 2;
            const int col = n ^ ((iiV & 7) << 3);
            const float4 va = tv[2 * pass], vb = tv[2 * pass + 1];
            const float a0[4] = {va.x, va.y, va.z, va.w};
            const float b0[4] = {vb.x, vb.y, vb.z, vb.w};
            #pragma unroll
            for (int c = 0; c < 4; ++c) {
                bf16x2 h = {(__bf16)a0[c], (__bf16)b0[c]};
                *(bf16x2*)&lk[(iiV * 4 + c) * 256 + col] = h;
            }
        }
        __syncthreads();

        f32x4 acc2[2] = {};
        #pragma unroll
        for (int ks = 0; ks < 8; ++ks) {
            const bf16x8 bfrag = *(bf16x8*)&lk[dRow * 256 + ((ks * 32 + hi * 8) ^ key)];
            #pragma unroll
            for (int am = 0; am < 2; ++am) {
                const int prow = ph * 32 + am * 16 + l15;
                const bf16x8 afrag = *(bf16x8*)&lp[prow * LP_STRIDE + ks * 32 + hi * 8];
                acc2[am] = mfma16(afrag, bfrag, acc2[am]);
            }
        }
        #pragma unroll
        for (int am = 0; am < 2; ++am)
            #pragma unroll
            for (int j = 0; j < 4; ++j) {
                const int p = ph * 32 + am * 16 + hi * 4 + j;
                const int d = d0 + dq * 16 + l15;
                part[(((size_t)sp * BB + b) * PP + p) * DD + d] = (_Float16)acc2[am][j];
            }
    }
}

// ---------------------------------------------------------------------------
// Combine: out[b,p,d] = sum_sp exp(m_sp - M) * part[sp,b,p,d] / D,
//          D = sum_c exp(m_c - M) * l_c.
// ---------------------------------------------------------------------------
__global__ __launch_bounds__(256) void k_combine(const _Float16* __restrict__ part,
                                                 const float* __restrict__ statm,
                                                 const float* __restrict__ statl,
                                                 float* __restrict__ out) {
    const size_t idx = (size_t)blockIdx.x * 256 + threadIdx.x;  // f32x4 units
    const size_t e = idx * 4;
    const int bp = (int)(e / DD);
    const int b = bp >> 6, p = bp & 63;

    float M = -1e30f;
    #pragma unroll
    for (int c = 0; c < 16; ++c) M = fmaxf(M, statm[((size_t)b * 16 + c) * 64 + p]);
    float Ee[16];
    float D = 0.f;
    #pragma unroll
    for (int c = 0; c < 16; ++c) {
        Ee[c] = __expf(statm[((size_t)b * 16 + c) * 64 + p] - M);
        D += Ee[c] * statl[((size_t)b * 16 + c) * 64 + p];
    }
    const float inv = 1.f / D;

    float4 v = {0.f, 0.f, 0.f, 0.f};
    #pragma unroll
    for (int c = 0; c < 16; ++c) {
        const f16x4 h = *(const f16x4*)&part[(size_t)c * ((size_t)BB * PP * DD) + e];
        v.x += Ee[c] * (float)h[0];
        v.y += Ee[c] * (float)h[1];
        v.z += Ee[c] * (float)h[2];
        v.w += Ee[c] * (float)h[3];
    }
    v.x *= inv; v.y *= inv; v.z *= inv; v.w *= inv;
    *(float4*)&out[e] = v;
}

extern "C" void kernel_launch(void* const* d_in, const int* in_sizes, int n_in,
                              void* d_out, int out_size, void* d_ws, size_t ws_size,
                              hipStream_t stream) {
    const float* x = (const float*)d_in[0];   // [16, 4096, 768]
    const float* q = (const float*)d_in[1];   // [16, 64, 768]
    float* out = (float*)d_out;               // [16, 64, 768]

    char* ws = (char*)d_ws;
    float*     statm = (float*)ws;                       // 64 KB [16][16][64]
    float*     statl = (float*)(ws + 65536);             // 64 KB
    _Float16*  part  = (_Float16*)(ws + 131072);         // 24 MB [16][16][64][768]

    hipLaunchKernelGGL(k_fused,   dim3(256), dim3(512), 0, stream, x, q, statm, statl, part);
    hipLaunchKernelGGL(k_combine, dim3(768), dim3(256), 0, stream, part, statm, statl, out);
}

// Round 5
// 112.970 us; speedup vs baseline: 1.1266x; 1.1266x over previous
//
#include <hip/hip_runtime.h>
#include <hip/hip_bf16.h>

// Shapes
#define BB 16
#define PP 64
#define NN 4096
#define DD 768

typedef __attribute__((ext_vector_type(4))) float f32x4;
typedef __attribute__((ext_vector_type(8))) __bf16 bf16x8;
typedef __attribute__((ext_vector_type(4))) __bf16 bf16x4;
typedef __attribute__((ext_vector_type(2))) __bf16 bf16x2;
typedef __attribute__((ext_vector_type(4))) _Float16 f16x4;

__device__ __forceinline__ f32x4 mfma16(bf16x8 a, bf16x8 b, f32x4 c) {
    return __builtin_amdgcn_mfma_f32_16x16x32_bf16(a, b, c, 0, 0, 0);
}

// XOR swizzle for phase-1 K/Q tiles: 8 distinct keys across any 8 consecutive
// rows -> both b128 frag reads (16 consecutive rows) and stage writes are
// <=2-way (free). Key granularity 8 elems = 16 B preserves b128 contiguity.
__device__ __forceinline__ int SW(int r) { return (r & 7) << 3; }

// P buffer row stride (elems). 520 B: softmax scalar writes spread across
// 32B windows; frag reads 2-way free.
#define LP_STRIDE 260

// LDS layout (bytes):
//   [0,      32768)  lk: phase1 K tile [256][64] swizzled / phase2 V^T [64][256] swizzled
//   [32768,  40960)  lq: Q tile [64][64] swizzled
//   [40960,  74240)  lp: P [64][LP_STRIDE] bf16
//   [74240,  76288)  wred [8][64] f32
//   [76288,  76544)  mfin [64] f32
#define SM_BYTES 76544

// ---------------------------------------------------------------------------
// Fused: per (b, 256-token chunk): QK^T -> local softmax (P in LDS) -> PV.
// Writes fp16 partial [64 p][768 d] and per-chunk stats (m, l).
// grid 256 = 16 b x 16 chunks; block 512 (8 waves).
// __launch_bounds__(512, 2): 2 waves/EU minimum -> VGPR cap 256, so the
// 8-deep batched loads stay resident and issue unwaited (round-4 fix).
// ---------------------------------------------------------------------------
__global__ __launch_bounds__(512, 2) void k_fused(const float* __restrict__ x,
                                                  const float* __restrict__ q,
                                                  float* __restrict__ statm,
                                                  float* __restrict__ statl,
                                                  _Float16* __restrict__ part) {
    const int b  = blockIdx.x >> 4;
    const int sp = blockIdx.x & 15;
    const int n0 = sp * 256;

    __shared__ char smem[SM_BYTES];
    __bf16* lk   = (__bf16*)smem;
    __bf16* lq   = (__bf16*)(smem + 32768);
    __bf16* lp   = (__bf16*)(smem + 40960);
    float*  wred = (float*)(smem + 74240);
    float*  mfin = (float*)(smem + 76288);

    const int t = threadIdx.x;
    const int w = t >> 6, lane = t & 63;
    const int l15 = lane & 15, hi = lane >> 4;

    const int rK = t >> 1, hK = t & 1;      // K-tile row / 32-float half
    const int rQ = (t & 127) >> 1, hQ = t & 1;

    f32x4 acc[4][2] = {};

    const size_t xrow = ((size_t)b * NN + n0 + rK) * DD + hK * 32;
    const size_t qrow = ((size_t)b * PP + rQ) * DD + hQ * 32;

    // ============================ Phase 1: QK^T ============================
    float4 tk[8], tq[8];
    #pragma unroll
    for (int i = 0; i < 8; ++i) tk[i] = *(const float4*)&x[xrow + 4 * i];
    if (t < 128) {
        #pragma unroll
        for (int i = 0; i < 8; ++i) tq[i] = *(const float4*)&q[qrow + 4 * i];
    }

    for (int kd = 0; kd < DD; kd += 64) {
        __syncthreads();   // prev iter's frag reads done
        // ---- stage current regs -> LDS (swizzled) ----
        #pragma unroll
        for (int j = 0; j < 4; ++j) {
            const float4 a = tk[2 * j], c = tk[2 * j + 1];
            bf16x8 h = {(__bf16)a.x, (__bf16)a.y, (__bf16)a.z, (__bf16)a.w,
                        (__bf16)c.x, (__bf16)c.y, (__bf16)c.z, (__bf16)c.w};
            *(bf16x8*)&lk[rK * 64 + ((hK * 32 + 8 * j) ^ SW(rK))] = h;
        }
        if (t < 128) {
            #pragma unroll
            for (int j = 0; j < 4; ++j) {
                const float4 a = tq[2 * j], c = tq[2 * j + 1];
                bf16x8 h = {(__bf16)a.x, (__bf16)a.y, (__bf16)a.z, (__bf16)a.w,
                            (__bf16)c.x, (__bf16)c.y, (__bf16)c.z, (__bf16)c.w};
                *(bf16x8*)&lq[rQ * 64 + ((hQ * 32 + 8 * j) ^ SW(rQ))] = h;
            }
        }
        // ---- prefetch next kd tile (in flight across MFMA + barriers) ----
        if (kd + 64 < DD) {
            #pragma unroll
            for (int i = 0; i < 8; ++i) tk[i] = *(const float4*)&x[xrow + kd + 64 + 4 * i];
            if (t < 128) {
                #pragma unroll
                for (int i = 0; i < 8; ++i) tq[i] = *(const float4*)&q[qrow + kd + 64 + 4 * i];
            }
        }
        __syncthreads();
        // ---- MFMA ----
        #pragma unroll
        for (int ks = 0; ks < 2; ++ks) {
            bf16x8 af[4], bfr[2];
            #pragma unroll
            for (int am = 0; am < 4; ++am) {
                const int r = am * 16 + l15;
                af[am] = *(bf16x8*)&lq[r * 64 + ((ks * 32 + hi * 8) ^ SW(r))];
            }
            #pragma unroll
            for (int an = 0; an < 2; ++an) {
                const int r = w * 32 + an * 16 + l15;
                bfr[an] = *(bf16x8*)&lk[r * 64 + ((ks * 32 + hi * 8) ^ SW(r))];
            }
            #pragma unroll
            for (int am = 0; am < 4; ++am)
                #pragma unroll
                for (int an = 0; an < 2; ++an)
                    acc[am][an] = mfma16(af[am], bfr[an], acc[am][an]);
        }
    }

    // ---- prefetch phase-2 V tile for d0=0 (hidden under softmax VALU) ----
    const int iiV = t & 15;      // d float4 col
    const int rrV = t >> 4;      // n-pair base
    float4 tv[8];
    #pragma unroll
    for (int pass = 0; pass < 4; ++pass) {
        const int n = pass * 64 + rrV * 2;
        tv[2 * pass]     = *(const float4*)&x[((size_t)b * NN + n0 + n) * DD + iiV * 4];
        tv[2 * pass + 1] = *(const float4*)&x[((size_t)b * NN + n0 + n + 1) * DD + iiV * 4];
    }

    // ==================== local softmax (P stays in LDS) ====================
    const float scale = 0.036084391824351615f;  // 768^-0.5
    float sv[4][2][4];
    #pragma unroll
    for (int am = 0; am < 4; ++am)
        #pragma unroll
        for (int an = 0; an < 2; ++an)
            #pragma unroll
            for (int j = 0; j < 4; ++j) sv[am][an][j] = acc[am][an][j] * scale;

    float pm[4][4];
    #pragma unroll
    for (int am = 0; am < 4; ++am)
        #pragma unroll
        for (int j = 0; j < 4; ++j) pm[am][j] = fmaxf(sv[am][0][j], sv[am][1][j]);
    #pragma unroll
    for (int off = 1; off < 16; off <<= 1)
        #pragma unroll
        for (int am = 0; am < 4; ++am)
            #pragma unroll
            for (int j = 0; j < 4; ++j) pm[am][j] = fmaxf(pm[am][j], __shfl_xor(pm[am][j], off));
    if (l15 == 0)
        #pragma unroll
        for (int am = 0; am < 4; ++am)
            #pragma unroll
            for (int j = 0; j < 4; ++j) wred[w * 64 + am * 16 + hi * 4 + j] = pm[am][j];
    __syncthreads();
    if (t < 64) {
        float m = wred[t];
        #pragma unroll
        for (int ww = 1; ww < 8; ++ww) m = fmaxf(m, wred[ww * 64 + t]);
        mfin[t] = m;
    }
    __syncthreads();

    float ls[4][4] = {};
    #pragma unroll
    for (int am = 0; am < 4; ++am)
        #pragma unroll
        for (int j = 0; j < 4; ++j) {
            const int p = am * 16 + hi * 4 + j;
            const float m = mfin[p];
            #pragma unroll
            for (int an = 0; an < 2; ++an) {
                const float e = __expf(sv[am][an][j] - m);
                ls[am][j] += e;
                lp[p * LP_STRIDE + w * 32 + an * 16 + l15] = (__bf16)e;
            }
        }
    #pragma unroll
    for (int off = 1; off < 16; off <<= 1)
        #pragma unroll
        for (int am = 0; am < 4; ++am)
            #pragma unroll
            for (int j = 0; j < 4; ++j) ls[am][j] += __shfl_xor(ls[am][j], off);
    if (l15 == 0)
        #pragma unroll
        for (int am = 0; am < 4; ++am)
            #pragma unroll
            for (int j = 0; j < 4; ++j) wred[w * 64 + am * 16 + hi * 4 + j] = ls[am][j];
    __syncthreads();
    if (t < 64) {
        float l = 0.f;
        #pragma unroll
        for (int ww = 0; ww < 8; ++ww) l += wred[ww * 64 + t];
        const size_t si = ((size_t)b * 16 + sp) * 64 + t;
        statm[si] = mfin[t];
        statl[si] = l;
    }

    // ============================ Phase 2: PV ==============================
    // V^T staged into lk region: [64 d][256 n], col = n ^ ((d>>2 & 7)<<3)
    // (write-free banks; reads 4-way -- writes dominate instr count).
    const int ph = w >> 2, dq = w & 3;
    const int dRow = dq * 16 + l15;
    const int key = ((dRow >> 2) & 7) << 3;

    for (int d0 = 0; d0 < DD; d0 += 64) {
        __syncthreads();   // prev iter reads done; first iter: fences lp writes
        // ---- stage V^T from regs ----
        #pragma unroll
        for (int pass = 0; pass < 4; ++pass) {
            const int n = pass * 64 + rrV * 2;
            const int col = n ^ ((iiV & 7) << 3);
            const float4 va = tv[2 * pass], vb = tv[2 * pass + 1];
            const float a0[4] = {va.x, va.y, va.z, va.w};
            const float b0[4] = {vb.x, vb.y, vb.z, vb.w};
            #pragma unroll
            for (int c = 0; c < 4; ++c) {
                bf16x2 h = {(__bf16)a0[c], (__bf16)b0[c]};
                *(bf16x2*)&lk[(iiV * 4 + c) * 256 + col] = h;
            }
        }
        // ---- prefetch next d0 tile ----
        if (d0 + 64 < DD) {
            #pragma unroll
            for (int pass = 0; pass < 4; ++pass) {
                const int n = pass * 64 + rrV * 2;
                tv[2 * pass]     = *(const float4*)&x[((size_t)b * NN + n0 + n) * DD + d0 + 64 + iiV * 4];
                tv[2 * pass + 1] = *(const float4*)&x[((size_t)b * NN + n0 + n + 1) * DD + d0 + 64 + iiV * 4];
            }
        }
        __syncthreads();

        f32x4 acc2[2] = {};
        #pragma unroll
        for (int ks = 0; ks < 8; ++ks) {
            const bf16x8 bfrag = *(bf16x8*)&lk[dRow * 256 + ((ks * 32 + hi * 8) ^ key)];
            #pragma unroll
            for (int am = 0; am < 2; ++am) {
                const int prow = ph * 32 + am * 16 + l15;
                const bf16x8 afrag = *(bf16x8*)&lp[prow * LP_STRIDE + ks * 32 + hi * 8];
                acc2[am] = mfma16(afrag, bfrag, acc2[am]);
            }
        }
        #pragma unroll
        for (int am = 0; am < 2; ++am)
            #pragma unroll
            for (int j = 0; j < 4; ++j) {
                const int p = ph * 32 + am * 16 + hi * 4 + j;
                const int d = d0 + dq * 16 + l15;
                part[(((size_t)sp * BB + b) * PP + p) * DD + d] = (_Float16)acc2[am][j];
            }
    }
}

// ---------------------------------------------------------------------------
// Combine: out[b,p,d] = sum_sp exp(m_sp - M) * part[sp,b,p,d] / D,
//          D = sum_c exp(m_c - M) * l_c.
// ---------------------------------------------------------------------------
__global__ __launch_bounds__(256) void k_combine(const _Float16* __restrict__ part,
                                                 const float* __restrict__ statm,
                                                 const float* __restrict__ statl,
                                                 float* __restrict__ out) {
    const size_t idx = (size_t)blockIdx.x * 256 + threadIdx.x;  // f32x4 units
    const size_t e = idx * 4;
    const int bp = (int)(e / DD);
    const int b = bp >> 6, p = bp & 63;

    float M = -1e30f;
    #pragma unroll
    for (int c = 0; c < 16; ++c) M = fmaxf(M, statm[((size_t)b * 16 + c) * 64 + p]);
    float Ee[16];
    float D = 0.f;
    #pragma unroll
    for (int c = 0; c < 16; ++c) {
        Ee[c] = __expf(statm[((size_t)b * 16 + c) * 64 + p] - M);
        D += Ee[c] * statl[((size_t)b * 16 + c) * 64 + p];
    }
    const float inv = 1.f / D;

    float4 v = {0.f, 0.f, 0.f, 0.f};
    #pragma unroll
    for (int c = 0; c < 16; ++c) {
        const f16x4 h = *(const f16x4*)&part[(size_t)c * ((size_t)BB * PP * DD) + e];
        v.x += Ee[c] * (float)h[0];
        v.y += Ee[c] * (float)h[1];
        v.z += Ee[c] * (float)h[2];
        v.w += Ee[c] * (float)h[3];
    }
    v.x *= inv; v.y *= inv; v.z *= inv; v.w *= inv;
    *(float4*)&out[e] = v;
}

extern "C" void kernel_launch(void* const* d_in, const int* in_sizes, int n_in,
                              void* d_out, int out_size, void* d_ws, size_t ws_size,
                              hipStream_t stream) {
    const float* x = (const float*)d_in[0];   // [16, 4096, 768]
    const float* q = (const float*)d_in[1];   // [16, 64, 768]
    float* out = (float*)d_out;               // [16, 64, 768]

    char* ws = (char*)d_ws;
    float*     statm = (float*)ws;                       // 64 KB [16][16][64]
    float*     statl = (float*)(ws + 65536);             // 64 KB
    _Float16*  part  = (_Float16*)(ws + 131072);         // 24 MB [16][16][64][768]

    hipLaunchKernelGGL(k_fused,   dim3(256), dim3(512), 0, stream, x, q, statm, statl, part);
    hipLaunchKernelGGL(k_combine, dim3(768), dim3(256), 0, stream, part, statm, statl, out);
}

// Round 7
// 102.972 us; speedup vs baseline: 1.2360x; 1.0971x over previous
//
#include <hip/hip_runtime.h>
#include <hip/hip_bf16.h>

// Shapes
#define BB 16
#define PP 64
#define NN 4096
#define DD 768

typedef __attribute__((ext_vector_type(4))) float f32x4;
typedef __attribute__((ext_vector_type(8))) __bf16 bf16x8;
typedef __attribute__((ext_vector_type(4))) _Float16 f16x4;

__device__ __forceinline__ f32x4 mfma16(bf16x8 a, bf16x8 b, f32x4 c) {
    return __builtin_amdgcn_mfma_f32_16x16x32_bf16(a, b, c, 0, 0, 0);
}

// Async global->LDS DMA, 16 B per lane. LDS dest = wave-uniform base + lane*16.
__device__ __forceinline__ void gl_lds(const float* g, float* l) {
    __builtin_amdgcn_global_load_lds(
        (const __attribute__((address_space(1))) void*)g,
        (__attribute__((address_space(3))) void*)l, 16, 0, 0);
}

#define S_WAITCNT_VM(N) asm volatile("s_waitcnt vmcnt(" #N ")" ::: "memory")
#define BARRIER() do { __builtin_amdgcn_s_barrier(); asm volatile("" ::: "memory"); } while (0)

// Read 8 consecutive f32 (k-granules hi*2, hi*2+1) from a source-swizzled row
// (granule slot s holds global granule s ^ (row&7)), convert to bf16x8.
__device__ __forceinline__ bf16x8 fragf32(const float* rowbase, int hi, int r) {
    const int k = r & 7;
    const f32x4 lo = *(const f32x4*)(rowbase + (((hi * 2)     ^ k) << 2));
    const f32x4 hg = *(const f32x4*)(rowbase + (((hi * 2 + 1) ^ k) << 2));
    bf16x8 h = {(__bf16)lo[0], (__bf16)lo[1], (__bf16)lo[2], (__bf16)lo[3],
                (__bf16)hg[0], (__bf16)hg[1], (__bf16)hg[2], (__bf16)hg[3]};
    return h;
}

#define LP_STRIDE 260

// LDS (bytes):
//   [0,      65536)  kbuf[2][256*32] f32   (phase2: vbuf[2][128*64] f32)
//   [65536,  81920)  qbuf[2][64*32] f32
//   [81920, 115200)  lp [64][LP_STRIDE] bf16
//   [115200,117248)  wred [8][64] f32
//   [117248,117504)  mfin [64] f32
#define SM_BYTES 117504

// ---------------------------------------------------------------------------
// Fused per (b, 256-token chunk): QK^T -> local softmax (P in LDS) -> PV.
// All global->LDS staging via async DMA, double-buffered, counted vmcnt.
// grid 256 = 16 b x 16 chunks; block 512 (8 waves).
// ---------------------------------------------------------------------------
__global__ __launch_bounds__(512, 2) void k_fused(const float* __restrict__ x,
                                                  const float* __restrict__ q,
                                                  float* __restrict__ statm,
                                                  float* __restrict__ statl,
                                                  _Float16* __restrict__ part) {
    const int b  = blockIdx.x >> 4;
    const int sp = blockIdx.x & 15;
    const int n0 = sp * 256;

    __shared__ __align__(16) char smem[SM_BYTES];
    float* kqbase = (float*)smem;                    // kbuf / vbuf
    float* qbase  = (float*)(smem + 65536);
    __bf16* lp    = (__bf16*)(smem + 81920);
    float*  wred  = (float*)(smem + 115200);
    float*  mfin  = (float*)(smem + 117248);

    const int t = threadIdx.x;
    const int w = t >> 6, lane = t & 63;
    const int l15 = lane & 15, hi = lane >> 4;

    f32x4 acc[4][2] = {};

    // ============================ Phase 1: QK^T ============================
    // Stage kd-tile kt into buffer buf: K [256][32]f32 (4 issues/wave) +
    // Q [64][32]f32 (1 issue/wave). Source granule pre-swizzled by row&7.
    const size_t xchunk = (size_t)b * NN + n0;
    const size_t qchunk = (size_t)b * PP;

#define STAGE1(buf, kt) do {                                                  \
        const int kd_ = (kt) * 32;                                            \
        float* kb_ = kqbase + (buf) * (256 * 32);                             \
        _Pragma("unroll")                                                     \
        for (int i_ = 0; i_ < 4; ++i_) {                                      \
            const int R_ = w * 32 + i_ * 8;                                   \
            const int r_ = R_ + (lane >> 3);                                  \
            const int gg_ = ((lane & 7) ^ (r_ & 7)) << 2;                     \
            gl_lds(&x[(xchunk + r_) * DD + kd_ + gg_], kb_ + R_ * 32);        \
        }                                                                     \
        float* qb_ = qbase + (buf) * (64 * 32);                               \
        const int Rq_ = w * 8;                                                \
        const int rq_ = Rq_ + (lane >> 3);                                    \
        const int ggq_ = ((lane & 7) ^ (rq_ & 7)) << 2;                       \
        gl_lds(&q[(qchunk + rq_) * DD + kd_ + ggq_], qb_ + Rq_ * 32);         \
    } while (0)

    STAGE1(0, 0);
    int cur = 0;
    for (int kt = 0; kt < 24; ++kt) {
        if (kt < 23) { STAGE1(cur ^ 1, kt + 1); S_WAITCNT_VM(5); }
        else         { S_WAITCNT_VM(0); }
        BARRIER();
        const float* kb = kqbase + cur * (256 * 32);
        const float* qb = qbase  + cur * (64 * 32);
        bf16x8 af[4], bfr[2];
        #pragma unroll
        for (int am = 0; am < 4; ++am) {
            const int r = am * 16 + l15;
            af[am] = fragf32(qb + r * 32, hi, r);
        }
        #pragma unroll
        for (int an = 0; an < 2; ++an) {
            const int r = w * 32 + an * 16 + l15;
            bfr[an] = fragf32(kb + r * 32, hi, r);
        }
        #pragma unroll
        for (int am = 0; am < 4; ++am)
            #pragma unroll
            for (int an = 0; an < 2; ++an)
                acc[am][an] = mfma16(af[am], bfr[an], acc[am][an]);
        BARRIER();
        cur ^= 1;
    }

    // ==================== local softmax (P stays in LDS) ====================
    const float scale = 0.036084391824351615f;  // 768^-0.5
    float sv[4][2][4];
    #pragma unroll
    for (int am = 0; am < 4; ++am)
        #pragma unroll
        for (int an = 0; an < 2; ++an)
            #pragma unroll
            for (int j = 0; j < 4; ++j) sv[am][an][j] = acc[am][an][j] * scale;

    float pm[4][4];
    #pragma unroll
    for (int am = 0; am < 4; ++am)
        #pragma unroll
        for (int j = 0; j < 4; ++j) pm[am][j] = fmaxf(sv[am][0][j], sv[am][1][j]);
    #pragma unroll
    for (int off = 1; off < 16; off <<= 1)
        #pragma unroll
        for (int am = 0; am < 4; ++am)
            #pragma unroll
            for (int j = 0; j < 4; ++j) pm[am][j] = fmaxf(pm[am][j], __shfl_xor(pm[am][j], off));
    if (l15 == 0)
        #pragma unroll
        for (int am = 0; am < 4; ++am)
            #pragma unroll
            for (int j = 0; j < 4; ++j) wred[w * 64 + am * 16 + hi * 4 + j] = pm[am][j];
    __syncthreads();
    if (t < 64) {
        float m = wred[t];
        #pragma unroll
        for (int ww = 1; ww < 8; ++ww) m = fmaxf(m, wred[ww * 64 + t]);
        mfin[t] = m;
    }
    __syncthreads();

    float ls[4][4] = {};
    #pragma unroll
    for (int am = 0; am < 4; ++am)
        #pragma unroll
        for (int j = 0; j < 4; ++j) {
            const int p = am * 16 + hi * 4 + j;
            const float m = mfin[p];
            #pragma unroll
            for (int an = 0; an < 2; ++an) {
                const float e = __expf(sv[am][an][j] - m);
                ls[am][j] += e;
                lp[p * LP_STRIDE + w * 32 + an * 16 + l15] = (__bf16)e;
            }
        }
    #pragma unroll
    for (int off = 1; off < 16; off <<= 1)
        #pragma unroll
        for (int am = 0; am < 4; ++am)
            #pragma unroll
            for (int j = 0; j < 4; ++j) ls[am][j] += __shfl_xor(ls[am][j], off);
    if (l15 == 0)
        #pragma unroll
        for (int am = 0; am < 4; ++am)
            #pragma unroll
            for (int j = 0; j < 4; ++j) wred[w * 64 + am * 16 + hi * 4 + j] = ls[am][j];
    __syncthreads();
    if (t < 64) {
        float l = 0.f;
        #pragma unroll
        for (int ww = 0; ww < 8; ++ww) l += wred[ww * 64 + t];
        const size_t si = ((size_t)b * 16 + sp) * 64 + t;
        statm[si] = mfin[t];
        statl[si] = l;
    }
    __syncthreads();   // lp visible; all phase-1 LDS reads done before vbuf DMA

    // ============================ Phase 2: PV ==============================
    // 24 steps s = d0idx*2 + nh: V tile x[n0+nh*128 .. +128][d0 .. d0+64] f32,
    // DMA'd n-major [128][64] with n-keyed granule swizzle; B-frags via b32
    // gathers (exactly 2 lanes/bank). ks = 0..3 covers ALL 128 staged rows
    // (round-6 bug: ks stopped at 2 -> half the tokens never accumulated).
    const int ph = w >> 2, dq = w & 3;
    const int d = dq * 16 + l15;

#define STAGE2(buf, s) do {                                                   \
        const int d0_ = ((s) >> 1) * 64, nh_ = (s) & 1;                       \
        float* vb_ = kqbase + (buf) * (128 * 64);                             \
        _Pragma("unroll")                                                     \
        for (int i_ = 0; i_ < 4; ++i_) {                                      \
            const int R_ = w * 16 + i_ * 4;                                   \
            const int n_ = R_ + (lane >> 4);                                  \
            const int gg_ = ((lane & 15) ^ (((n_ >> 3) & 3) << 2)) << 2;      \
            gl_lds(&x[(xchunk + nh_ * 128 + n_) * DD + d0_ + gg_],            \
                   vb_ + R_ * 64);                                            \
        }                                                                     \
    } while (0)

    STAGE2(0, 0);
    cur = 0;
    f32x4 acc2[2] = {};
    for (int s = 0; s < 24; ++s) {
        if (s < 23) { STAGE2(cur ^ 1, s + 1); S_WAITCNT_VM(4); }
        else        { S_WAITCNT_VM(0); }
        BARRIER();
        const float* vb = kqbase + cur * (128 * 64);
        const int nh = s & 1;
        #pragma unroll
        for (int ks = 0; ks < 4; ++ks) {
            float vf[8];
            #pragma unroll
            for (int i = 0; i < 8; ++i) {
                const int n = ks * 32 + hi * 8 + i;        // 0..127 within tile
                const int gg = (d >> 2) ^ (((n >> 3) & 3) << 2);
                vf[i] = vb[n * 64 + gg * 4 + (d & 3)];
            }
            bf16x8 bfrag = {(__bf16)vf[0], (__bf16)vf[1], (__bf16)vf[2], (__bf16)vf[3],
                            (__bf16)vf[4], (__bf16)vf[5], (__bf16)vf[6], (__bf16)vf[7]};
            #pragma unroll
            for (int am = 0; am < 2; ++am) {
                const int prow = ph * 32 + am * 16 + l15;
                const bf16x8 afrag =
                    *(const bf16x8*)&lp[prow * LP_STRIDE + nh * 128 + ks * 32 + hi * 8];
                acc2[am] = mfma16(afrag, bfrag, acc2[am]);
            }
        }
        BARRIER();
        if (s & 1) {   // chunk's n fully accumulated for this d0: flush
            const int d0 = (s >> 1) * 64;
            #pragma unroll
            for (int am = 0; am < 2; ++am) {
                #pragma unroll
                for (int j = 0; j < 4; ++j) {
                    const int p = ph * 32 + am * 16 + hi * 4 + j;
                    part[(((size_t)sp * BB + b) * PP + p) * DD + d0 + d] = (_Float16)acc2[am][j];
                }
                acc2[am] = (f32x4){0.f, 0.f, 0.f, 0.f};
            }
        }
        cur ^= 1;
    }
}

// ---------------------------------------------------------------------------
// Combine: out[b,p,d] = sum_sp exp(m_sp - M) * part[sp,b,p,d] / D,
//          D = sum_c exp(m_c - M) * l_c.
// ---------------------------------------------------------------------------
__global__ __launch_bounds__(256) void k_combine(const _Float16* __restrict__ part,
                                                 const float* __restrict__ statm,
                                                 const float* __restrict__ statl,
                                                 float* __restrict__ out) {
    const size_t idx = (size_t)blockIdx.x * 256 + threadIdx.x;  // f32x4 units
    const size_t e = idx * 4;
    const int bp = (int)(e / DD);
    const int b = bp >> 6, p = bp & 63;

    float M = -1e30f;
    #pragma unroll
    for (int c = 0; c < 16; ++c) M = fmaxf(M, statm[((size_t)b * 16 + c) * 64 + p]);
    float Ee[16];
    float D = 0.f;
    #pragma unroll
    for (int c = 0; c < 16; ++c) {
        Ee[c] = __expf(statm[((size_t)b * 16 + c) * 64 + p] - M);
        D += Ee[c] * statl[((size_t)b * 16 + c) * 64 + p];
    }
    const float inv = 1.f / D;

    float4 v = {0.f, 0.f, 0.f, 0.f};
    #pragma unroll
    for (int c = 0; c < 16; ++c) {
        const f16x4 h = *(const f16x4*)&part[(size_t)c * ((size_t)BB * PP * DD) + e];
        v.x += Ee[c] * (float)h[0];
        v.y += Ee[c] * (float)h[1];
        v.z += Ee[c] * (float)h[2];
        v.w += Ee[c] * (float)h[3];
    }
    v.x *= inv; v.y *= inv; v.z *= inv; v.w *= inv;
    *(float4*)&out[e] = v;
}

extern "C" void kernel_launch(void* const* d_in, const int* in_sizes, int n_in,
                              void* d_out, int out_size, void* d_ws, size_t ws_size,
                              hipStream_t stream) {
    const float* x = (const float*)d_in[0];   // [16, 4096, 768]
    const float* q = (const float*)d_in[1];   // [16, 64, 768]
    float* out = (float*)d_out;               // [16, 64, 768]

    char* ws = (char*)d_ws;
    float*     statm = (float*)ws;                       // 64 KB [16][16][64]
    float*     statl = (float*)(ws + 65536);             // 64 KB
    _Float16*  part  = (_Float16*)(ws + 131072);         // 24 MB [16][16][64][768]

    hipLaunchKernelGGL(k_fused,   dim3(256), dim3(512), 0, stream, x, q, statm, statl, part);
    hipLaunchKernelGGL(k_combine, dim3(768), dim3(256), 0, stream, part, statm, statl, out);
}

// Round 8
// 102.023 us; speedup vs baseline: 1.2475x; 1.0093x over previous
//
#include <hip/hip_runtime.h>
#include <hip/hip_bf16.h>

// Shapes
#define BB 16
#define PP 64
#define NN 4096
#define DD 768

typedef __attribute__((ext_vector_type(4))) float f32x4;
typedef __attribute__((ext_vector_type(8))) __bf16 bf16x8;
typedef __attribute__((ext_vector_type(4))) _Float16 f16x4;

__device__ __forceinline__ f32x4 mfma16(bf16x8 a, bf16x8 b, f32x4 c) {
    return __builtin_amdgcn_mfma_f32_16x16x32_bf16(a, b, c, 0, 0, 0);
}

// Async global->LDS DMA, 16 B per lane. LDS dest = wave-uniform base + lane*16.
__device__ __forceinline__ void gl_lds(const float* g, float* l) {
    __builtin_amdgcn_global_load_lds(
        (const __attribute__((address_space(1))) void*)g,
        (__attribute__((address_space(3))) void*)l, 16, 0, 0);
}

#define S_WAITCNT_VM(N) asm volatile("s_waitcnt vmcnt(" #N ")" ::: "memory")
#define S_WAITCNT_VM_LGKM(N) asm volatile("s_waitcnt vmcnt(" #N ") lgkmcnt(0)" ::: "memory")
#define BARRIER() do { __builtin_amdgcn_s_barrier(); asm volatile("" ::: "memory"); } while (0)
// LDS-only barrier: does NOT drain vmcnt (keeps DMA prefetch in flight).
#define LDS_BARRIER() do { asm volatile("s_waitcnt lgkmcnt(0)" ::: "memory"); \
                           __builtin_amdgcn_s_barrier(); \
                           __builtin_amdgcn_sched_barrier(0); } while (0)

// Read 8 consecutive f32 (k-granules hi*2, hi*2+1) from a source-swizzled row
// (granule slot s holds global granule s ^ (row&7)), convert to bf16x8.
__device__ __forceinline__ bf16x8 fragf32(const float* rowbase, int hi, int r) {
    const int k = r & 7;
    const f32x4 lo = *(const f32x4*)(rowbase + (((hi * 2)     ^ k) << 2));
    const f32x4 hg = *(const f32x4*)(rowbase + (((hi * 2 + 1) ^ k) << 2));
    bf16x8 h = {(__bf16)lo[0], (__bf16)lo[1], (__bf16)lo[2], (__bf16)lo[3],
                (__bf16)hg[0], (__bf16)hg[1], (__bf16)hg[2], (__bf16)hg[3]};
    return h;
}

#define LP_STRIDE 260

// LDS (bytes):
//   [0,      98304)  kbuf[3][256*32] f32   (phase2: vbuf[3][128*64] f32)
//   [98304, 122880)  qbuf[3][64*32] f32
//   [122880,156160)  lp [64][LP_STRIDE] bf16
//   [156160,158208)  wred [8][64] f32
//   [158208,158464)  mfin [64] f32
#define SM_BYTES 158464

// ---------------------------------------------------------------------------
// Fused per (b, 256-token chunk): QK^T -> local softmax (P in LDS) -> PV.
// DMA staging, TRIPLE-buffered (2-tile latency window), counted vmcnt.
// grid 256 = 16 b x 16 chunks; block 512 (8 waves), 1 block/CU.
// ---------------------------------------------------------------------------
__global__ __launch_bounds__(512, 2) void k_fused(const float* __restrict__ x,
                                                  const float* __restrict__ q,
                                                  float* __restrict__ statm,
                                                  float* __restrict__ statl,
                                                  _Float16* __restrict__ part) {
    const int b  = blockIdx.x >> 4;
    const int sp = blockIdx.x & 15;
    const int n0 = sp * 256;

    __shared__ __align__(16) char smem[SM_BYTES];
    float* kqbase = (float*)smem;                    // kbuf / vbuf
    float* qbase  = (float*)(smem + 98304);
    __bf16* lp    = (__bf16*)(smem + 122880);
    float*  wred  = (float*)(smem + 156160);
    float*  mfin  = (float*)(smem + 158208);

    const int t = threadIdx.x;
    const int w = t >> 6, lane = t & 63;
    const int l15 = lane & 15, hi = lane >> 4;

    f32x4 acc[4][2] = {};

    // ============================ Phase 1: QK^T ============================
    const size_t xchunk = (size_t)b * NN + n0;
    const size_t qchunk = (size_t)b * PP;

#define STAGE1(buf, kt) do {                                                  \
        const int kd_ = (kt) * 32;                                            \
        float* kb_ = kqbase + (buf) * (256 * 32);                             \
        _Pragma("unroll")                                                     \
        for (int i_ = 0; i_ < 4; ++i_) {                                      \
            const int R_ = w * 32 + i_ * 8;                                   \
            const int r_ = R_ + (lane >> 3);                                  \
            const int gg_ = ((lane & 7) ^ (r_ & 7)) << 2;                     \
            gl_lds(&x[(xchunk + r_) * DD + kd_ + gg_], kb_ + R_ * 32);        \
        }                                                                     \
        float* qb_ = qbase + (buf) * (64 * 32);                               \
        const int Rq_ = w * 8;                                                \
        const int rq_ = Rq_ + (lane >> 3);                                    \
        const int ggq_ = ((lane & 7) ^ (rq_ & 7)) << 2;                       \
        gl_lds(&q[(qchunk + rq_) * DD + kd_ + ggq_], qb_ + Rq_ * 32);         \
    } while (0)

    STAGE1(0, 0);
    STAGE1(1, 1);
    int cb = 0;                      // compute-buffer index = kt % 3
    for (int kt = 0; kt < 24; ++kt) {
        if (kt < 22) {
            const int sb = (cb == 0) ? 2 : cb - 1;   // (kt+2) % 3
            STAGE1(sb, kt + 2);
            S_WAITCNT_VM(10);        // tiles kt+1, kt+2 stay in flight
        } else if (kt == 22) { S_WAITCNT_VM(5); }
        else                 { S_WAITCNT_VM(0); }
        BARRIER();
        const float* kb = kqbase + cb * (256 * 32);
        const float* qb = qbase  + cb * (64 * 32);
        bf16x8 af[4], bfr[2];
        #pragma unroll
        for (int am = 0; am < 4; ++am) {
            const int r = am * 16 + l15;
            af[am] = fragf32(qb + r * 32, hi, r);
        }
        #pragma unroll
        for (int an = 0; an < 2; ++an) {
            const int r = w * 32 + an * 16 + l15;
            bfr[an] = fragf32(kb + r * 32, hi, r);
        }
        #pragma unroll
        for (int am = 0; am < 4; ++am)
            #pragma unroll
            for (int an = 0; an < 2; ++an)
                acc[am][an] = mfma16(af[am], bfr[an], acc[am][an]);
        BARRIER();
        cb = (cb == 2) ? 0 : cb + 1;
    }

    // ---- phase-2 V prefetch (tiles 0,1) BEFORE softmax: latency hides ----
    const int ph = w >> 2, dq = w & 3;
    const int d = dq * 16 + l15;

#define STAGE2(buf, s) do {                                                   \
        const int d0_ = ((s) >> 1) * 64, nh_ = (s) & 1;                       \
        float* vb_ = kqbase + (buf) * (128 * 64);                             \
        _Pragma("unroll")                                                     \
        for (int i_ = 0; i_ < 4; ++i_) {                                      \
            const int R_ = w * 16 + i_ * 4;                                   \
            const int n_ = R_ + (lane >> 4);                                  \
            const int gg_ = ((lane & 15) ^ (((n_ >> 3) & 3) << 2)) << 2;      \
            gl_lds(&x[(xchunk + nh_ * 128 + n_) * DD + d0_ + gg_],            \
                   vb_ + R_ * 64);                                            \
        }                                                                     \
    } while (0)

    STAGE2(0, 0);
    STAGE2(1, 1);

    // ==================== local softmax (P stays in LDS) ====================
    // All barriers here are LDS-only (no vmcnt drain -> V DMA stays in flight).
    const float scale = 0.036084391824351615f;  // 768^-0.5
    float sv[4][2][4];
    #pragma unroll
    for (int am = 0; am < 4; ++am)
        #pragma unroll
        for (int an = 0; an < 2; ++an)
            #pragma unroll
            for (int j = 0; j < 4; ++j) sv[am][an][j] = acc[am][an][j] * scale;

    float pm[4][4];
    #pragma unroll
    for (int am = 0; am < 4; ++am)
        #pragma unroll
        for (int j = 0; j < 4; ++j) pm[am][j] = fmaxf(sv[am][0][j], sv[am][1][j]);
    #pragma unroll
    for (int off = 1; off < 16; off <<= 1)
        #pragma unroll
        for (int am = 0; am < 4; ++am)
            #pragma unroll
            for (int j = 0; j < 4; ++j) pm[am][j] = fmaxf(pm[am][j], __shfl_xor(pm[am][j], off));
    if (l15 == 0)
        #pragma unroll
        for (int am = 0; am < 4; ++am)
            #pragma unroll
            for (int j = 0; j < 4; ++j) wred[w * 64 + am * 16 + hi * 4 + j] = pm[am][j];
    LDS_BARRIER();
    if (t < 64) {
        float m = wred[t];
        #pragma unroll
        for (int ww = 1; ww < 8; ++ww) m = fmaxf(m, wred[ww * 64 + t]);
        mfin[t] = m;
    }
    LDS_BARRIER();

    float ls[4][4] = {};
    #pragma unroll
    for (int am = 0; am < 4; ++am)
        #pragma unroll
        for (int j = 0; j < 4; ++j) {
            const int p = am * 16 + hi * 4 + j;
            const float m = mfin[p];
            #pragma unroll
            for (int an = 0; an < 2; ++an) {
                const float e = __expf(sv[am][an][j] - m);
                ls[am][j] += e;
                lp[p * LP_STRIDE + w * 32 + an * 16 + l15] = (__bf16)e;
            }
        }
    #pragma unroll
    for (int off = 1; off < 16; off <<= 1)
        #pragma unroll
        for (int am = 0; am < 4; ++am)
            #pragma unroll
            for (int j = 0; j < 4; ++j) ls[am][j] += __shfl_xor(ls[am][j], off);
    if (l15 == 0)
        #pragma unroll
        for (int am = 0; am < 4; ++am)
            #pragma unroll
            for (int j = 0; j < 4; ++j) wred[w * 64 + am * 16 + hi * 4 + j] = ls[am][j];
    LDS_BARRIER();
    if (t < 64) {
        float l = 0.f;
        #pragma unroll
        for (int ww = 0; ww < 8; ++ww) l += wred[ww * 64 + t];
        const size_t si = ((size_t)b * 16 + sp) * 64 + t;
        statm[si] = mfin[t];
        statl[si] = l;
    }
    // lp-write visibility for phase 2 is fenced by the first loop wait below
    // (vmcnt+lgkmcnt(0)) + BARRIER.

    // ============================ Phase 2: PV ==============================
    // 24 steps s = d0idx*2 + nh. vbuf[3] triple-buffered; B-frags via b32
    // gathers (2 lanes/bank, free).
    int cb2 = 0;
    f32x4 acc2[2] = {};
    for (int s = 0; s < 24; ++s) {
        if (s < 22) {
            const int sb = (cb2 == 0) ? 2 : cb2 - 1;   // (s+2) % 3
            STAGE2(sb, s + 2);
            S_WAITCNT_VM_LGKM(8);
        } else if (s == 22) { S_WAITCNT_VM_LGKM(4); }
        else                { S_WAITCNT_VM_LGKM(0); }
        BARRIER();
        const float* vb = kqbase + cb2 * (128 * 64);
        const int nh = s & 1;
        #pragma unroll
        for (int ks = 0; ks < 4; ++ks) {
            float vf[8];
            #pragma unroll
            for (int i = 0; i < 8; ++i) {
                const int n = ks * 32 + hi * 8 + i;        // 0..127 within tile
                const int gg = (d >> 2) ^ (((n >> 3) & 3) << 2);
                vf[i] = vb[n * 64 + gg * 4 + (d & 3)];
            }
            bf16x8 bfrag = {(__bf16)vf[0], (__bf16)vf[1], (__bf16)vf[2], (__bf16)vf[3],
                            (__bf16)vf[4], (__bf16)vf[5], (__bf16)vf[6], (__bf16)vf[7]};
            #pragma unroll
            for (int am = 0; am < 2; ++am) {
                const int prow = ph * 32 + am * 16 + l15;
                const bf16x8 afrag =
                    *(const bf16x8*)&lp[prow * LP_STRIDE + nh * 128 + ks * 32 + hi * 8];
                acc2[am] = mfma16(afrag, bfrag, acc2[am]);
            }
        }
        BARRIER();
        if (s & 1) {   // chunk's n fully accumulated for this d0: flush
            const int d0 = (s >> 1) * 64;
            #pragma unroll
            for (int am = 0; am < 2; ++am) {
                #pragma unroll
                for (int j = 0; j < 4; ++j) {
                    const int p = ph * 32 + am * 16 + hi * 4 + j;
                    part[(((size_t)sp * BB + b) * PP + p) * DD + d0 + d] = (_Float16)acc2[am][j];
                }
                acc2[am] = (f32x4){0.f, 0.f, 0.f, 0.f};
            }
        }
        cb2 = (cb2 == 2) ? 0 : cb2 + 1;
    }
}

// ---------------------------------------------------------------------------
// Combine: out[b,p,d] = sum_sp exp(m_sp - M) * part[sp,b,p,d] / D,
//          D = sum_c exp(m_c - M) * l_c.
// ---------------------------------------------------------------------------
__global__ __launch_bounds__(256) void k_combine(const _Float16* __restrict__ part,
                                                 const float* __restrict__ statm,
                                                 const float* __restrict__ statl,
                                                 float* __restrict__ out) {
    const size_t idx = (size_t)blockIdx.x * 256 + threadIdx.x;  // f32x4 units
    const size_t e = idx * 4;
    const int bp = (int)(e / DD);
    const int b = bp >> 6, p = bp & 63;

    float M = -1e30f;
    #pragma unroll
    for (int c = 0; c < 16; ++c) M = fmaxf(M, statm[((size_t)b * 16 + c) * 64 + p]);
    float Ee[16];
    float D = 0.f;
    #pragma unroll
    for (int c = 0; c < 16; ++c) {
        Ee[c] = __expf(statm[((size_t)b * 16 + c) * 64 + p] - M);
        D += Ee[c] * statl[((size_t)b * 16 + c) * 64 + p];
    }
    const float inv = 1.f / D;

    float4 v = {0.f, 0.f, 0.f, 0.f};
    #pragma unroll
    for (int c = 0; c < 16; ++c) {
        const f16x4 h = *(const f16x4*)&part[(size_t)c * ((size_t)BB * PP * DD) + e];
        v.x += Ee[c] * (float)h[0];
        v.y += Ee[c] * (float)h[1];
        v.z += Ee[c] * (float)h[2];
        v.w += Ee[c] * (float)h[3];
    }
    v.x *= inv; v.y *= inv; v.z *= inv; v.w *= inv;
    *(float4*)&out[e] = v;
}

extern "C" void kernel_launch(void* const* d_in, const int* in_sizes, int n_in,
                              void* d_out, int out_size, void* d_ws, size_t ws_size,
                              hipStream_t stream) {
    const float* x = (const float*)d_in[0];   // [16, 4096, 768]
    const float* q = (const float*)d_in[1];   // [16, 64, 768]
    float* out = (float*)d_out;               // [16, 64, 768]

    char* ws = (char*)d_ws;
    float*     statm = (float*)ws;                       // 64 KB [16][16][64]
    float*     statl = (float*)(ws + 65536);             // 64 KB
    _Float16*  part  = (_Float16*)(ws + 131072);         // 24 MB [16][16][64][768]

    hipLaunchKernelGGL(k_fused,   dim3(256), dim3(512), 0, stream, x, q, statm, statl, part);
    hipLaunchKernelGGL(k_combine, dim3(768), dim3(256), 0, stream, part, statm, statl, out);
}

// Round 9
// 69.511 us; speedup vs baseline: 1.8310x; 1.4677x over previous
//
#include <hip/hip_runtime.h>
#include <hip/hip_bf16.h>

// Shapes
#define BB 16
#define PP 64
#define NN 4096
#define DD 768
#define TT 16      // tokens per tile
#define NTILE 16   // tiles per 256-token chunk

typedef __attribute__((ext_vector_type(4))) float f32x4;
typedef __attribute__((ext_vector_type(8))) __bf16 bf16x8;
typedef __attribute__((ext_vector_type(2))) __bf16 bf16x2;
typedef __attribute__((ext_vector_type(4))) _Float16 f16x4;

__device__ __forceinline__ f32x4 mfma16(bf16x8 a, bf16x8 b, f32x4 c) {
    return __builtin_amdgcn_mfma_f32_16x16x32_bf16(a, b, c, 0, 0, 0);
}

__device__ __forceinline__ void gl_lds(const float* g, float* l) {
    __builtin_amdgcn_global_load_lds(
        (const __attribute__((address_space(1))) void*)g,
        (__attribute__((address_space(3))) void*)l, 16, 0, 0);
}

#define S_WAITCNT_VM(N) asm volatile("s_waitcnt vmcnt(" #N ")" ::: "memory")
#define BARRIER() do { __builtin_amdgcn_s_barrier(); asm volatile("" ::: "memory"); } while (0)
// LDS-only barrier: drains ds ops, NOT vmcnt (DMA prefetch stays in flight).
#define LDS_BARRIER() do { asm volatile("s_waitcnt lgkmcnt(0)" ::: "memory"); \
                           __builtin_amdgcn_s_barrier(); \
                           __builtin_amdgcn_sched_barrier(0); } while (0)

// LDS layout (bytes):
//   [0,     98304)  vstage[2][16][768] f32 (source-granule XOR swizzle by row&7)
//   [98304,135168)  lpf[8][64][18] f32  (QK^T kd-slice partials, stride 18)
//   [135168,140288) pbuf[64][40] bf16   (P, k 0..15 live, 16..39 zero)
//   [140288,141056) mrun/lrun/rsc [64] f32 each
#define SM_BYTES 141056

// ---------------------------------------------------------------------------
// Flash: per (b, 256-token chunk), stream 16 tiles of 16 tokens x 768 d (f32)
// through LDS ONCE; per tile: QK^T -> online softmax -> PV into reg-resident O.
// grid 256 = 16 b x 16 chunks; block 512 (8 waves).
// ---------------------------------------------------------------------------
__global__ __launch_bounds__(512, 2) void k_flash(const float* __restrict__ x,
                                                  const float* __restrict__ q,
                                                  float* __restrict__ statm,
                                                  float* __restrict__ statl,
                                                  _Float16* __restrict__ part) {
    const int b  = blockIdx.x >> 4;
    const int sp = blockIdx.x & 15;
    const int n0 = sp * 256;

    __shared__ __align__(16) char smem[SM_BYTES];
    float*  vst  = (float*)smem;
    float*  lpf  = (float*)(smem + 98304);
    __bf16* pbuf = (__bf16*)(smem + 135168);
    float*  mrun = (float*)(smem + 140288);
    float*  lrun = (float*)(smem + 140544);
    float*  rsc  = (float*)(smem + 140800);

    const int t = threadIdx.x;
    const int w = t >> 6, lane = t & 63;
    const int l15 = lane & 15, hi = lane >> 4;

    const size_t xbase = (size_t)b * NN + n0;
    const size_t qbase = (size_t)b * PP;

    // ---- Q-fragment preload: wave w owns kd-slice [w*96, w*96+96) ----
    // qf[am][s] covers p-frag am, kd = w*96 + s*32 (+hi*8).
    bf16x8 qf[4][3];
    #pragma unroll
    for (int am = 0; am < 4; ++am)
        #pragma unroll
        for (int s = 0; s < 3; ++s) {
            const size_t off = (qbase + am * 16 + l15) * DD + w * 96 + s * 32 + hi * 8;
            const float4 a = *(const float4*)&q[off];
            const float4 c = *(const float4*)&q[off + 4];
            qf[am][s] = (bf16x8){(__bf16)a.x, (__bf16)a.y, (__bf16)a.z, (__bf16)a.w,
                                 (__bf16)c.x, (__bf16)c.y, (__bf16)c.z, (__bf16)c.w};
        }

    // ---- init: zero P pad region, running stats ----
    for (int i = t; i < 64 * 20; i += 512) ((unsigned*)pbuf)[i] = 0;
    if (t < 64) { mrun[t] = -1e30f; lrun[t] = 0.f; }

    // O accumulator: wave w owns d-slice [w*96, w*96+96): 4 p-frags x 6 d-frags.
    f32x4 O[4][6] = {};

#define STAGE(bufi, tile) do {                                                \
        float* vb_ = vst + (bufi) * (TT * DD);                                \
        _Pragma("unroll")                                                     \
        for (int i_ = 0; i_ < 6; ++i_) {                                      \
            const int idx_ = w * 6 + i_;                                      \
            const int r_   = idx_ / 3;                                        \
            const int gg_  = (((idx_ % 3) << 6) + lane) ^ (r_ & 7);           \
            gl_lds(&x[(xbase + (size_t)(tile) * TT + r_) * DD + (size_t)gg_ * 4], \
                   vb_ + idx_ * 256);                                         \
        }                                                                     \
    } while (0)

    STAGE(0, 0);

    const float scale = 0.036084391824351615f;  // 768^-0.5
    const int p_  = t >> 3;      // softmax row
    const int np_ = t & 7;       // softmax n-pair

    for (int tile = 0; tile < NTILE; ++tile) {
        if (tile < NTILE - 1) { STAGE((tile + 1) & 1, tile + 1); S_WAITCNT_VM(6); }
        else                  { S_WAITCNT_VM(0); }
        BARRIER();
        const float* vb = vst + (tile & 1) * (TT * DD);

        // ---- QK^T: wave w: kd in {w*96, +32, +64}, all 4 p-frags ----
        f32x4 acc[4] = {};
        #pragma unroll
        for (int s = 0; s < 3; ++s) {
            const int g0 = w * 24 + s * 8 + hi * 2;      // granule of kd+hi*8
            const int ky = l15 & 7;                       // row swizzle key
            const f32x4 lo = *(const f32x4*)(vb + l15 * DD + ((g0 ^ ky) << 2));
            const f32x4 hg = *(const f32x4*)(vb + l15 * DD + (((g0 + 1) ^ ky) << 2));
            const bf16x8 kf = {(__bf16)lo[0], (__bf16)lo[1], (__bf16)lo[2], (__bf16)lo[3],
                               (__bf16)hg[0], (__bf16)hg[1], (__bf16)hg[2], (__bf16)hg[3]};
            #pragma unroll
            for (int am = 0; am < 4; ++am) acc[am] = mfma16(qf[am][s], kf, acc[am]);
        }
        #pragma unroll
        for (int am = 0; am < 4; ++am)
            #pragma unroll
            for (int j = 0; j < 4; ++j)
                lpf[(w * 64 + am * 16 + hi * 4 + j) * 18 + l15] = acc[am][j];
        LDS_BARRIER();

        // ---- online softmax: 8 threads per p-row, 2 tokens each ----
        float s0 = 0.f, s1 = 0.f;
        #pragma unroll
        for (int sl = 0; sl < 8; ++sl) {
            const float2 v2 = *(const float2*)&lpf[(sl * 64 + p_) * 18 + 2 * np_];
            s0 += v2.x; s1 += v2.y;
        }
        s0 *= scale; s1 *= scale;
        float mt = fmaxf(s0, s1);
        mt = fmaxf(mt, __shfl_xor(mt, 1));
        mt = fmaxf(mt, __shfl_xor(mt, 2));
        mt = fmaxf(mt, __shfl_xor(mt, 4));
        const float mo = mrun[p_];
        const float mn = fmaxf(mo, mt);
        const float e0 = __expf(s0 - mn), e1 = __expf(s1 - mn);
        float lsum = e0 + e1;
        lsum += __shfl_xor(lsum, 1);
        lsum += __shfl_xor(lsum, 2);
        lsum += __shfl_xor(lsum, 4);
        *(bf16x2*)&pbuf[p_ * 40 + 2 * np_] = (bf16x2){(__bf16)e0, (__bf16)e1};
        if (np_ == 0) {
            const float f = __expf(mo - mn);
            lrun[p_] = lrun[p_] * f + lsum;
            mrun[p_] = mn;
            rsc[p_]  = f;
        }
        LDS_BARRIER();

        // ---- O-rescale ----
        #pragma unroll
        for (int am = 0; am < 4; ++am)
            #pragma unroll
            for (int j = 0; j < 4; ++j) {
                const float f = rsc[am * 16 + hi * 4 + j];
                #pragma unroll
                for (int df = 0; df < 6; ++df) O[am][df][j] *= f;
            }

        // ---- PV: A = P (K=16 live, upper 16 zero), B = V gathers ----
        bf16x8 pf[4];
        #pragma unroll
        for (int am = 0; am < 4; ++am)
            pf[am] = *(const bf16x8*)&pbuf[(am * 16 + l15) * 40 + hi * 8];
        #pragma unroll
        for (int df = 0; df < 6; ++df) {
            const int d_ = w * 96 + df * 16 + l15;
            const int gd = d_ >> 2, dw = d_ & 3;
            float vf[8];
            #pragma unroll
            for (int i = 0; i < 8; ++i) {
                const int k_ = (hi * 8 + i) & 15;   // k>=16 -> A is zero, any row ok
                vf[i] = vb[k_ * DD + ((gd ^ i) << 2) + dw];
            }
            const bf16x8 vfr = {(__bf16)vf[0], (__bf16)vf[1], (__bf16)vf[2], (__bf16)vf[3],
                                (__bf16)vf[4], (__bf16)vf[5], (__bf16)vf[6], (__bf16)vf[7]};
            #pragma unroll
            for (int am = 0; am < 4; ++am) O[am][df] = mfma16(pf[am], vfr, O[am][df]);
        }
        LDS_BARRIER();
    }

    // ---- epilogue: stats + unnormalized O to part (f16) ----
    if (t < 64) {
        const size_t si = ((size_t)b * 16 + sp) * 64 + t;
        statm[si] = mrun[t];
        statl[si] = lrun[t];
    }
    #pragma unroll
    for (int am = 0; am < 4; ++am)
        #pragma unroll
        for (int j = 0; j < 4; ++j) {
            const int p = am * 16 + hi * 4 + j;
            #pragma unroll
            for (int df = 0; df < 6; ++df) {
                const int d_ = w * 96 + df * 16 + l15;
                part[(((size_t)sp * BB + b) * PP + p) * DD + d_] = (_Float16)O[am][df][j];
            }
        }
}

// ---------------------------------------------------------------------------
// Combine: out[b,p,d] = sum_sp exp(m_sp - M) * part[sp,b,p,d] / D,
//          D = sum_c exp(m_c - M) * l_c.
// ---------------------------------------------------------------------------
__global__ __launch_bounds__(256) void k_combine(const _Float16* __restrict__ part,
                                                 const float* __restrict__ statm,
                                                 const float* __restrict__ statl,
                                                 float* __restrict__ out) {
    const size_t idx = (size_t)blockIdx.x * 256 + threadIdx.x;  // f32x4 units
    const size_t e = idx * 4;
    const int bp = (int)(e / DD);
    const int b = bp >> 6, p = bp & 63;

    float M = -1e30f;
    #pragma unroll
    for (int c = 0; c < 16; ++c) M = fmaxf(M, statm[((size_t)b * 16 + c) * 64 + p]);
    float Ee[16];
    float D = 0.f;
    #pragma unroll
    for (int c = 0; c < 16; ++c) {
        Ee[c] = __expf(statm[((size_t)b * 16 + c) * 64 + p] - M);
        D += Ee[c] * statl[((size_t)b * 16 + c) * 64 + p];
    }
    const float inv = 1.f / D;

    float4 v = {0.f, 0.f, 0.f, 0.f};
    #pragma unroll
    for (int c = 0; c < 16; ++c) {
        const f16x4 h = *(const f16x4*)&part[(size_t)c * ((size_t)BB * PP * DD) + e];
        v.x += Ee[c] * (float)h[0];
        v.y += Ee[c] * (float)h[1];
        v.z += Ee[c] * (float)h[2];
        v.w += Ee[c] * (float)h[3];
    }
    v.x *= inv; v.y *= inv; v.z *= inv; v.w *= inv;
    *(float4*)&out[e] = v;
}

extern "C" void kernel_launch(void* const* d_in, const int* in_sizes, int n_in,
                              void* d_out, int out_size, void* d_ws, size_t ws_size,
                              hipStream_t stream) {
    const float* x = (const float*)d_in[0];   // [16, 4096, 768]
    const float* q = (const float*)d_in[1];   // [16, 64, 768]
    float* out = (float*)d_out;               // [16, 64, 768]

    char* ws = (char*)d_ws;
    float*     statm = (float*)ws;                       // 64 KB [16][16][64]
    float*     statl = (float*)(ws + 65536);             // 64 KB
    _Float16*  part  = (_Float16*)(ws + 131072);         // 24 MB [16][16][64][768]

    hipLaunchKernelGGL(k_flash,   dim3(256), dim3(512), 0, stream, x, q, statm, statl, part);
    hipLaunchKernelGGL(k_combine, dim3(768), dim3(256), 0, stream, part, statm, statl, out);
}

// Round 10
// 61.808 us; speedup vs baseline: 2.0592x; 1.1246x over previous
//
#include <hip/hip_runtime.h>
#include <hip/hip_bf16.h>

// Shapes
#define BB 16
#define PP 64
#define NN 4096
#define DD 768
#define TT 16      // tokens per tile
#define NTILE 16   // tiles per 256-token chunk
#define VROW 772   // padded LDS row stride (f32): 772 % 32 == 4 -> bank-spread rows

typedef __attribute__((ext_vector_type(4))) float f32x4;
typedef __attribute__((ext_vector_type(8))) __bf16 bf16x8;
typedef __attribute__((ext_vector_type(2))) __bf16 bf16x2;
typedef __attribute__((ext_vector_type(4))) short s16x4;
typedef __attribute__((ext_vector_type(4))) _Float16 f16x4;

#if __has_builtin(__builtin_amdgcn_mfma_f32_16x16x16bf16_1k)
#define HAVE_K16 1
#define PSTRIDE 20
#else
#define HAVE_K16 0
#define PSTRIDE 40
#endif

__device__ __forceinline__ f32x4 mfma16(bf16x8 a, bf16x8 b, f32x4 c) {
    return __builtin_amdgcn_mfma_f32_16x16x32_bf16(a, b, c, 0, 0, 0);
}

__device__ __forceinline__ void gl_lds(const float* g, float* l) {
    __builtin_amdgcn_global_load_lds(
        (const __attribute__((address_space(1))) void*)g,
        (__attribute__((address_space(3))) void*)l, 16, 0, 0);
}

__device__ __forceinline__ short bf2s(float f) {
    __bf16 h = (__bf16)f;
    return *(short*)&h;
}

#define S_WAITCNT_VM(N) asm volatile("s_waitcnt vmcnt(" #N ")" ::: "memory")
#define BARRIER() do { __builtin_amdgcn_s_barrier(); asm volatile("" ::: "memory"); } while (0)
// LDS-only barrier: drains ds ops, NOT vmcnt (DMA prefetch stays in flight).
#define LDS_BARRIER() do { asm volatile("s_waitcnt lgkmcnt(0)" ::: "memory"); \
                           __builtin_amdgcn_s_barrier(); \
                           __builtin_amdgcn_sched_barrier(0); } while (0)

// LDS layout (bytes):
//   [0,      98816)  vstage[2][16][772] f32  (row-padded; NO swizzle anywhere)
//   [98816, 135680)  lpf[8][64][18] f32      (QK^T kd-slice partials)
//   [135680,140800)  pbuf[64][PSTRIDE] bf16  (P tile)
//   [140800,141568)  mrun/lrun/rsc [64] f32 each
#define SM_BYTES 141568

// ---------------------------------------------------------------------------
// Flash: per (b, 256-token chunk), stream 16 tiles of 16 tokens x 768 d (f32)
// through LDS ONCE; per tile: QK^T -> online softmax -> PV into reg-resident O.
// grid 256 = 16 b x 16 chunks; block 512 (8 waves).
// ---------------------------------------------------------------------------
__global__ __launch_bounds__(512, 2) void k_flash(const float* __restrict__ x,
                                                  const float* __restrict__ q,
                                                  float* __restrict__ statm,
                                                  float* __restrict__ statl,
                                                  _Float16* __restrict__ part) {
    const int b  = blockIdx.x >> 4;
    const int sp = blockIdx.x & 15;
    const int n0 = sp * 256;

    __shared__ __align__(16) char smem[SM_BYTES];
    float*  vst  = (float*)smem;
    float*  lpf  = (float*)(smem + 98816);
    __bf16* pbuf = (__bf16*)(smem + 135680);
    float*  mrun = (float*)(smem + 140800);
    float*  lrun = (float*)(smem + 141056);
    float*  rsc  = (float*)(smem + 141312);

    const int t = threadIdx.x;
    const int w = t >> 6, lane = t & 63;
    const int l15 = lane & 15, hi = lane >> 4;

    const size_t xbase = (size_t)b * NN + n0;
    const size_t qbase = (size_t)b * PP;

    // ---- Q-fragment preload: wave w owns kd-slice [w*96, w*96+96) ----
    bf16x8 qf[4][3];
    #pragma unroll
    for (int am = 0; am < 4; ++am)
        #pragma unroll
        for (int s = 0; s < 3; ++s) {
            const size_t off = (qbase + am * 16 + l15) * DD + w * 96 + s * 32 + hi * 8;
            const float4 a = *(const float4*)&q[off];
            const float4 c = *(const float4*)&q[off + 4];
            qf[am][s] = (bf16x8){(__bf16)a.x, (__bf16)a.y, (__bf16)a.z, (__bf16)a.w,
                                 (__bf16)c.x, (__bf16)c.y, (__bf16)c.z, (__bf16)c.w};
        }

#if !HAVE_K16
    for (int i = t; i < 64 * PSTRIDE / 2; i += 512) ((unsigned*)pbuf)[i] = 0;
#endif
    if (t < 64) { mrun[t] = -1e30f; lrun[t] = 0.f; }

    // O accumulator: wave w owns d-slice [w*96, w*96+96): 4 p-frags x 6 d-frags.
    f32x4 O[4][6] = {};

    // Linear staging: issue idx (0..47) covers row idx/3, 256-f32 third idx%3.
    // Source = fully coalesced 1 KB; dest = padded row base (16B-aligned).
#define STAGE(bufi, tile) do {                                                \
        float* vb_ = vst + (bufi) * (TT * VROW);                              \
        _Pragma("unroll")                                                     \
        for (int i_ = 0; i_ < 6; ++i_) {                                      \
            const int idx_ = w * 6 + i_;                                      \
            const int r_ = idx_ / 3, c_ = idx_ % 3;                           \
            gl_lds(&x[(xbase + (size_t)(tile) * TT + r_) * DD + c_ * 256 + lane * 4], \
                   vb_ + r_ * VROW + c_ * 256);                               \
        }                                                                     \
    } while (0)

    STAGE(0, 0);

    const float scale = 0.036084391824351615f;  // 768^-0.5
    const int p_  = t >> 3;      // softmax row
    const int np_ = t & 7;       // softmax n-pair

    for (int tile = 0; tile < NTILE; ++tile) {
        if (tile < NTILE - 1) { STAGE((tile + 1) & 1, tile + 1); S_WAITCNT_VM(6); }
        else                  { S_WAITCNT_VM(0); }
        BARRIER();
        const float* vb = vst + (tile & 1) * (TT * VROW);

        // ---- QK^T: wave w: kd in {w*96, +32, +64}, all 4 p-frags ----
        f32x4 acc[4] = {};
        #pragma unroll
        for (int s = 0; s < 3; ++s) {
            const int g0 = w * 24 + s * 8 + hi * 2;      // f32x4 granule index
            const float* kp = vb + l15 * VROW + g0 * 4;
            const f32x4 lo = *(const f32x4*)kp;
            const f32x4 hg = *(const f32x4*)(kp + 4);
            const bf16x8 kf = {(__bf16)lo[0], (__bf16)lo[1], (__bf16)lo[2], (__bf16)lo[3],
                               (__bf16)hg[0], (__bf16)hg[1], (__bf16)hg[2], (__bf16)hg[3]};
            #pragma unroll
            for (int am = 0; am < 4; ++am) acc[am] = mfma16(qf[am][s], kf, acc[am]);
        }
        #pragma unroll
        for (int am = 0; am < 4; ++am)
            #pragma unroll
            for (int j = 0; j < 4; ++j)
                lpf[(w * 64 + am * 16 + hi * 4 + j) * 18 + l15] = acc[am][j];
        LDS_BARRIER();

        // ---- online softmax: 8 threads per p-row, 2 tokens each ----
        float s0 = 0.f, s1 = 0.f;
        #pragma unroll
        for (int sl = 0; sl < 8; ++sl) {
            const float2 v2 = *(const float2*)&lpf[(sl * 64 + p_) * 18 + 2 * np_];
            s0 += v2.x; s1 += v2.y;
        }
        s0 *= scale; s1 *= scale;
        float mt = fmaxf(s0, s1);
        mt = fmaxf(mt, __shfl_xor(mt, 1));
        mt = fmaxf(mt, __shfl_xor(mt, 2));
        mt = fmaxf(mt, __shfl_xor(mt, 4));
        const float mo = mrun[p_];
        const float mn = fmaxf(mo, mt);
        const float e0 = __expf(s0 - mn), e1 = __expf(s1 - mn);
        float lsum = e0 + e1;
        lsum += __shfl_xor(lsum, 1);
        lsum += __shfl_xor(lsum, 2);
        lsum += __shfl_xor(lsum, 4);
        *(bf16x2*)&pbuf[p_ * PSTRIDE + 2 * np_] = (bf16x2){(__bf16)e0, (__bf16)e1};
        if (np_ == 0) {
            const float f = __expf(mo - mn);
            lrun[p_] = lrun[p_] * f + lsum;
            mrun[p_] = mn;
            rsc[p_]  = f;
        }
        LDS_BARRIER();

        // ---- O-rescale ----
        #pragma unroll
        for (int am = 0; am < 4; ++am)
            #pragma unroll
            for (int j = 0; j < 4; ++j) {
                const float f = rsc[am * 16 + hi * 4 + j];
                #pragma unroll
                for (int df = 0; df < 6; ++df) O[am][df][j] *= f;
            }

#if HAVE_K16
        // ---- PV via K=16 MFMA: no pad, no duplicate V reads ----
        s16x4 pf[4];
        #pragma unroll
        for (int am = 0; am < 4; ++am)
            pf[am] = *(const s16x4*)&pbuf[(am * 16 + l15) * PSTRIDE + hi * 4];
        #pragma unroll
        for (int df = 0; df < 6; ++df) {
            const int d_ = w * 96 + df * 16 + l15;
            s16x4 vfr;
            #pragma unroll
            for (int i = 0; i < 4; ++i) {
                const int k_ = hi * 4 + i;
                vfr[i] = bf2s(vb[k_ * VROW + d_]);
            }
            #pragma unroll
            for (int am = 0; am < 4; ++am)
                O[am][df] = __builtin_amdgcn_mfma_f32_16x16x16bf16_1k(pf[am], vfr, O[am][df], 0, 0, 0);
        }
#else
        // ---- fallback: K=32 MFMA with zero-padded upper half ----
        bf16x8 pf[4];
        #pragma unroll
        for (int am = 0; am < 4; ++am)
            pf[am] = *(const bf16x8*)&pbuf[(am * 16 + l15) * PSTRIDE + hi * 8];
        #pragma unroll
        for (int df = 0; df < 6; ++df) {
            const int d_ = w * 96 + df * 16 + l15;
            float vf[8];
            #pragma unroll
            for (int i = 0; i < 8; ++i) {
                const int k_ = (hi * 8 + i) & 15;
                vf[i] = vb[k_ * VROW + d_];
            }
            const bf16x8 vfr = {(__bf16)vf[0], (__bf16)vf[1], (__bf16)vf[2], (__bf16)vf[3],
                                (__bf16)vf[4], (__bf16)vf[5], (__bf16)vf[6], (__bf16)vf[7]};
            #pragma unroll
            for (int am = 0; am < 4; ++am) O[am][df] = mfma16(pf[am], vfr, O[am][df]);
        }
#endif
        LDS_BARRIER();
    }

    // ---- epilogue: stats + unnormalized O to part (f16) ----
    if (t < 64) {
        const size_t si = ((size_t)b * 16 + sp) * 64 + t;
        statm[si] = mrun[t];
        statl[si] = lrun[t];
    }
    #pragma unroll
    for (int am = 0; am < 4; ++am)
        #pragma unroll
        for (int j = 0; j < 4; ++j) {
            const int p = am * 16 + hi * 4 + j;
            #pragma unroll
            for (int df = 0; df < 6; ++df) {
                const int d_ = w * 96 + df * 16 + l15;
                part[(((size_t)sp * BB + b) * PP + p) * DD + d_] = (_Float16)O[am][df][j];
            }
        }
}

// ---------------------------------------------------------------------------
// Combine: out[b,p,d] = sum_sp exp(m_sp - M) * part[sp,b,p,d] / D,
//          D = sum_c exp(m_c - M) * l_c.
// ---------------------------------------------------------------------------
__global__ __launch_bounds__(256) void k_combine(const _Float16* __restrict__ part,
                                                 const float* __restrict__ statm,
                                                 const float* __restrict__ statl,
                                                 float* __restrict__ out) {
    const size_t idx = (size_t)blockIdx.x * 256 + threadIdx.x;  // f32x4 units
    const size_t e = idx * 4;
    const int bp = (int)(e / DD);
    const int b = bp >> 6, p = bp & 63;

    float M = -1e30f;
    #pragma unroll
    for (int c = 0; c < 16; ++c) M = fmaxf(M, statm[((size_t)b * 16 + c) * 64 + p]);
    float Ee[16];
    float D = 0.f;
    #pragma unroll
    for (int c = 0; c < 16; ++c) {
        Ee[c] = __expf(statm[((size_t)b * 16 + c) * 64 + p] - M);
        D += Ee[c] * statl[((size_t)b * 16 + c) * 64 + p];
    }
    const float inv = 1.f / D;

    float4 v = {0.f, 0.f, 0.f, 0.f};
    #pragma unroll
    for (int c = 0; c < 16; ++c) {
        const f16x4 h = *(const f16x4*)&part[(size_t)c * ((size_t)BB * PP * DD) + e];
        v.x += Ee[c] * (float)h[0];
        v.y += Ee[c] * (float)h[1];
        v.z += Ee[c] * (float)h[2];
        v.w += Ee[c] * (float)h[3];
    }
    v.x *= inv; v.y *= inv; v.z *= inv; v.w *= inv;
    *(float4*)&out[e] = v;
}

extern "C" void kernel_launch(void* const* d_in, const int* in_sizes, int n_in,
                              void* d_out, int out_size, void* d_ws, size_t ws_size,
                              hipStream_t stream) {
    const float* x = (const float*)d_in[0];   // [16, 4096, 768]
    const float* q = (const float*)d_in[1];   // [16, 64, 768]
    float* out = (float*)d_out;               // [16, 64, 768]

    char* ws = (char*)d_ws;
    float*     statm = (float*)ws;                       // 64 KB [16][16][64]
    float*     statl = (float*)(ws + 65536);             // 64 KB
    _Float16*  part  = (_Float16*)(ws + 131072);         // 24 MB [16][16][64][768]

    hipLaunchKernelGGL(k_flash,   dim3(256), dim3(512), 0, stream, x, q, statm, statl, part);
    hipLaunchKernelGGL(k_combine, dim3(768), dim3(256), 0, stream, part, statm, statl, out);
}